// Round 14
// baseline (79.861 us; speedup 1.0000x reference)
//
#include <hip/hip_runtime.h>

// SbS hidden dynamics: per-pixel serial scan over T spikes.
#define BB      16
#define TT      128
#define XDIM    16
#define YDIM    16
#define IN_DIM  256
#define H_DIM   64
#define XY      (XDIM*YDIM)

// Round-14 = round-13 resubmitted (GPU-acquisition timeout; never ran).
// R12 kernel ~16us = ~300cyc/step vs ~100-130cyc chain+issue model: at
// 1 wave/SIMD every stall (DPP hazards, TRANS rcp latency, waitcnt) is
// exposed. 2048 waves = 2/SIMD lets two waves interleave issue.
// Permlane failures R3/4/9 re-diagnosed as INLINE-ASM REGISTER ALIASING:
// "+v"(pa),"+v"(pbv) with pa==pbv==r lets the compiler assign ONE register
// -> v_permlane32_swap v5,v5 self-swap -> s=2*half-sum: explains R3/R4
// (1.5e-3) AND R9 (8.7e-3, other half) under one theory. The BUILTIN
// returns distinct SSA results -> cannot alias:
//   res = __builtin_amdgcn_permlane32_swap(r,r,false,false)
//   s = res[0]+res[1]   (= r[lane&31]+r[lane|32] under either convention)
// Fallback (__has_builtin miss): __shfl_xor(r,32) — correct, +~30cyc chain.
//
// Layout (R3, staging/geometry verified): 2 px/wave; pixel p=(lane>>4)&1
// (A on rows {0,2}, B on rows {1,3}); ip=(lane&15)|((lane>>5)<<4) in [0,32);
// lane holds h[2ip..2ip+1] (float2); weights row = float2[32] coalesced.
// Reduce: quad_perm 0xB1/0x4E + row_ror 0x124/0x128 (R10/R11/R12-validated)
// -> 16-lane row sums all lanes; permlane32_swap pairs row0<->row2 (A),
// row1<->row3 (B) -> full 64-elem sum, within-pixel by construction.
// LDS group-batched (R12): spikes int4 (4 steps), P float4 (2 steps),
// weight rows prefetched one group (4 steps) ahead.
// 512 blocks = 2/CU, 2048 waves = 2/SIMD.

#define DPP_ADD(v, ctrl)                                                      \
    v += __int_as_float(__builtin_amdgcn_update_dpp(                          \
        0, __float_as_int(v), (ctrl), 0xf, 0xf, true))

__device__ __forceinline__ float cross_half_sum(float r) {
#if __has_builtin(__builtin_amdgcn_permlane32_swap)
    auto res = __builtin_amdgcn_permlane32_swap(
        __float_as_uint(r), __float_as_uint(r), false, false);
    return __uint_as_float(res[0]) + __uint_as_float(res[1]);
#else
    return r + __shfl_xor(r, 32);
#endif
}

// one scan step; reads/writes h (float2), uses W (float2), RD/ERD scalars
#define STEP(W, RD, ERD)                                                      \
    {                                                                         \
        const float ht0 = h.x * (W).x;                                        \
        const float ht1 = h.y * (W).y;                                        \
        float r = ht0 + ht1;                                                  \
        const float erdf = (ERD) * fo_h;                                      \
        const float eht0 = (ERD) * ht0;                                       \
        const float eht1 = (ERD) * ht1;                                       \
        const float t30 = fmaf(h.x, (RD), erdf);                              \
        const float t31 = fmaf(h.y, (RD), erdf);                              \
        DPP_ADD(r, 0xB1);   /* quad_perm xor1 */                              \
        DPP_ADD(r, 0x4E);   /* quad_perm xor2 -> quad sums */                 \
        DPP_ADD(r, 0x124);  /* row_ror:4 */                                   \
        DPP_ADD(r, 0x128);  /* row_ror:8 -> row sum in all 16 lanes */        \
        const float s = cross_half_sum(r);  /* full 64-elem pixel sum */      \
        const float rs = __builtin_amdgcn_rcpf(s); /* s>=1e-3 structurally */ \
        h.x = fmaf(rs, eht0, t30);                                            \
        h.y = fmaf(rs, eht1, t31);                                            \
    }

__global__ __launch_bounds__(256) void sbs_scan_kernel(
    const int*   __restrict__ spikes,   // [B,T,X,Y]
    const float* __restrict__ eps_xy,   // [IN,X,Y]
    const float* __restrict__ eps_t,    // [T]
    const float* __restrict__ weights,  // [IN,H]
    const float* __restrict__ h_init,   // [H]
    const float* __restrict__ fo_ptr,   // [1]
    float*       __restrict__ out)      // [B,H,X,Y]
{
    __shared__ int4   s_spk4[8][TT / 4 + 1];   // spikes, 4 steps/entry
    __shared__ float4 s_P4[8][TT / 2 + 1];     // (rd,erd)x2, 2 steps/entry
    __shared__ float  s_out[8][H_DIM + 1];     // output transpose

    const int tid = threadIdx.x;
    const int bi  = blockIdx.x;          // 512 blocks
    const int b   = bi >> 5;             // 16
    const int x   = (bi >> 1) & 15;      // 16
    const int y0  = (bi & 1) * 8;        // 2 groups of 8 y

    // ---- stage spikes: 1024 ints, 4 per thread (kept in regs for P pass) ----
    int spv[4];
    #pragma unroll
    for (int k = 0; k < 4; ++k) {
        const int idx = tid + k * 256;   // t = idx>>3, pb = idx&7
        const int t = idx >> 3, pb = idx & 7;
        const int sp = spikes[(b * TT + t) * XY + x * YDIM + y0 + pb];
        spv[k] = sp;
        ((int*)s_spk4[pb])[t] = sp;      // packed: entry t/4, comp t%4
    }

    const float fo   = fo_ptr[0];
    const float fo1  = 1.0f + fo;
    const float fo_h = fo * (1.0f / (float)H_DIM);

    // ---- per-step scalars: rd = 1/(1+eps(1+fo)) (NR, off-chain), erd ----
    #pragma unroll
    for (int k = 0; k < 4; ++k) {
        const int idx = tid + k * 256;
        const int t = idx >> 3, pb = idx & 7;
        const float eps = eps_xy[spv[k] * XY + x * YDIM + y0 + pb] * eps_t[t];
        const float den = fmaf(eps, fo1, 1.0f);
        float rd = __builtin_amdgcn_rcpf(den);
        rd = fmaf(rd, fmaf(-den, rd, 1.0f), rd);
        ((float2*)s_P4[pb])[t] = make_float2(rd, eps * rd);  // entry t/2
    }
    __syncthreads();

    // ---- per-lane geometry (R3 interleave): 2 px/wave ----
    const int wave = tid >> 6;
    const int lane = tid & 63;
    const int p    = (lane >> 4) & 1;                 // pixel-in-wave
    const int pb   = wave * 2 + p;                    // block-pixel 0..7
    const int ip   = (lane & 15) | ((lane >> 5) << 4); // 0..31

    const float2* __restrict__ w2 = (const float2*)weights;  // [IN][32]
    const int4*   __restrict__ Sy = s_spk4[pb];
    const float4* __restrict__ Py = s_P4[pb];

    float2 h = ((const float2*)h_init)[ip];

    // ---- queues (group = 4 steps; 32 groups) ----
    const int4 s0 = Sy[0];
    int4   sA  = Sy[1];
    int4   sB  = Sy[2];
    float2 wq0 = w2[s0.x * 32 + ip];
    float2 wq1 = w2[s0.y * 32 + ip];
    float2 wq2 = w2[s0.z * 32 + ip];
    float2 wq3 = w2[s0.w * 32 + ip];
    float4 PA0 = Py[0], PA1 = Py[1];     // group g
    float4 PB0 = Py[2], PB1 = Py[3];     // group g+1

    #pragma unroll 2
    for (int g = 0; g < TT / 4; ++g) {
        // group-level prefetches (issue->use distance: 8 steps LDS, 4 global)
        const int4   s_in  = Sy[(g + 3) & 31];
        const float4 p_in0 = Py[(2 * g + 4) & 63];
        const float4 p_in1 = Py[(2 * g + 5) & 63];
        const float2 wn0 = w2[sA.x * 32 + ip];
        const float2 wn1 = w2[sA.y * 32 + ip];
        const float2 wn2 = w2[sA.z * 32 + ip];
        const float2 wn3 = w2[sA.w * 32 + ip];

        STEP(wq0, PA0.x, PA0.y);
        STEP(wq1, PA0.z, PA0.w);
        STEP(wq2, PA1.x, PA1.y);
        STEP(wq3, PA1.z, PA1.w);

        wq0 = wn0; wq1 = wn1; wq2 = wn2; wq3 = wn3;
        PA0 = PB0; PA1 = PB1; PB0 = p_in0; PB1 = p_in1;
        sA = sB; sB = s_in;
    }

    // ---- output transpose: out[b, h, x, y] ----
    *(float2*)&s_out[pb][2 * ip] = h;
    __syncthreads();
    #pragma unroll
    for (int k = 0; k < 2; ++k) {
        const int idx = tid + k * 256;   // 512 = 64 h * 8 y
        const int hh = idx >> 3, p2 = idx & 7;
        out[b * (H_DIM * XY) + hh * XY + x * YDIM + y0 + p2] = s_out[p2][hh];
    }
}

extern "C" void kernel_launch(void* const* d_in, const int* in_sizes, int n_in,
                              void* d_out, int out_size, void* d_ws, size_t ws_size,
                              hipStream_t stream) {
    // inputs (setup_inputs order):
    // 0: input [B,IN,X,Y] f32 (unused)   1: spikes [B,T,X,Y] i32
    // 2: epsilon_xy [IN,X,Y] f32         3: epsilon_t_0 [T] f32
    // 4: weights [IN,H] f32              5: h_initial [H] f32
    // 6: forgetting_offset [1] f32
    const int*   spikes  = (const int*)  d_in[1];
    const float* eps_xy  = (const float*)d_in[2];
    const float* eps_t   = (const float*)d_in[3];
    const float* weights = (const float*)d_in[4];
    const float* h_init  = (const float*)d_in[5];
    const float* fo_ptr  = (const float*)d_in[6];
    float*       out     = (float*)d_out;

    const int grid = BB * XDIM * (YDIM / 8);   // 512 blocks, 2 px/wave
    sbs_scan_kernel<<<grid, 256, 0, stream>>>(
        spikes, eps_xy, eps_t, weights, h_init, fo_ptr, out);
}